// Round 1
// baseline (109.526 us; speedup 1.0000x reference)
//
#include <hip/hip_runtime.h>

#define HH 4096
#define WW 4096

__global__ __launch_bounds__(256) void bio_kernel(
    const float* __restrict__ v,
    const float* __restrict__ na,
    const float* __restrict__ kk,
    const float* __restrict__ ca,
    float* __restrict__ out)
{
    const int W4 = WW / 4;
    int tid = blockIdx.x * blockDim.x + threadIdx.x;
    if (tid >= HH * W4) return;
    int r  = tid / W4;
    int c4 = tid - r * W4;
    int c  = c4 * 4;
    long base = (long)r * WW + c;

    // reflect padding (mirror excluding edge): row 0's "up" is row 1, etc.
    int rup = (r == 0)      ? 1      : r - 1;
    int rdn = (r == HH - 1) ? HH - 2 : r + 1;

    float4 vc = *(const float4*)(v + base);
    float4 vu = *(const float4*)(v + (long)rup * WW + c);
    float4 vd = *(const float4*)(v + (long)rdn * WW + c);
    float vl = (c == 0)       ? v[(long)r * WW + 1]      : v[base - 1];
    float vr = (c + 4 == WW)  ? v[(long)r * WW + WW - 2] : v[base + 4];

    float4 na4 = *(const float4*)(na + base);
    float4 k4  = *(const float4*)(kk + base);
    float4 ca4 = *(const float4*)(ca + base);

    float cv[4]  = {vc.x, vc.y, vc.z, vc.w};
    float uu[4]  = {vu.x, vu.y, vu.z, vu.w};
    float dd[4]  = {vd.x, vd.y, vd.z, vd.w};
    float lft[4] = {vl,   vc.x, vc.y, vc.z};
    float rgt[4] = {vc.y, vc.z, vc.w, vr};
    float nain[4] = {na4.x, na4.y, na4.z, na4.w};
    float kin[4]  = {k4.x,  k4.y,  k4.z,  k4.w};
    float cain[4] = {ca4.x, ca4.y, ca4.z, ca4.w};

    float ov[4], ona[4], okk[4], oca[4];
#pragma unroll
    for (int i = 0; i < 4; ++i) {
        float lap = uu[i] + dd[i] + lft[i] + rgt[i] - 4.0f * cv[i];
        float vupd = 0.5f * lap + 0.1f * nain[i] - 0.05f * kin[i] + 0.08f * cain[i];
        float nv = tanhf(cv[i] + 0.1f * vupd);
        ov[i]  = nv;
        ona[i] = nain[i] * 0.95f + 0.05f * fmaxf(nv, 0.0f);
        okk[i] = kin[i]  * 0.95f + 0.05f * fmaxf(-nv, 0.0f);
        oca[i] = cain[i] * 0.95f + 0.05f * fabsf(nv);
    }

    const long HW = (long)HH * WW;
    *(float4*)(out + base)          = make_float4(ov[0],  ov[1],  ov[2],  ov[3]);
    *(float4*)(out + HW + base)     = make_float4(ona[0], ona[1], ona[2], ona[3]);
    *(float4*)(out + 2 * HW + base) = make_float4(okk[0], okk[1], okk[2], okk[3]);
    *(float4*)(out + 3 * HW + base) = make_float4(oca[0], oca[1], oca[2], oca[3]);
}

extern "C" void kernel_launch(void* const* d_in, const int* in_sizes, int n_in,
                              void* d_out, int out_size, void* d_ws, size_t ws_size,
                              hipStream_t stream) {
    const float* v  = (const float*)d_in[0];
    const float* na = (const float*)d_in[1];
    const float* kk = (const float*)d_in[2];
    const float* ca = (const float*)d_in[3];
    float* out = (float*)d_out;

    int total = HH * (WW / 4);
    int block = 256;
    int grid = (total + block - 1) / block;
    bio_kernel<<<grid, block, 0, stream>>>(v, na, kk, ca, out);
}